// Round 1
// 846.643 us; speedup vs baseline: 1.0301x; 1.0301x over previous
//
#include <hip/hip_runtime.h>
#include <stdint.h>

// ---------------------------------------------------------------------------
// TransformerBlock: rmsnorm -> QKV -> RoPE -> causal flash attn -> +x ->
//                   rmsnorm -> swiglu FFN -> +O
// bf16 MFMA everywhere; Q/K path uses hi/lo bf16 split (3-pass MFMA) because
// softmax is near-one-hot on scores with sigma~900.
// R7: flash_k latency attack (was 55% stall: MfmaUtil 12%, VALU 32%, HBM 13%):
//  (a) K/V LDS double-buffered + counted s_waitcnt vmcnt(6) prefetch (T3/T4):
//      tile kt+1's 6 global_load_lds stay in flight across the barrier while
//      tile kt computes. Raw s_barrier (not __syncthreads) so the compiler's
//      vmcnt(0)-before-barrier drain is avoided. 2 barriers/iter as before.
//  (b) dropped the mid-iteration __syncthreads (P[w] is wave-private; the
//      ds_write->ds_read dependency is intra-wave, compiler emits lgkmcnt).
//  (c) causal mask only on diagonal tiles (wave-uniform branch); 1/8 scale +
//      log2e folded into one fma + v_exp per element (raw-score domain).
//  (d) s_setprio(1) around MFMA clusters (m191: +4-7% attn).
// R6: (a) flash_k load balance - grid (8,64), q-tile PAIR (qt, 15-qt) = 34
// KV-iters per block. (b) separate w1/w3 GEMMs + swiglu (R5 fusion regressed).
// ---------------------------------------------------------------------------

typedef short bf16x8 __attribute__((ext_vector_type(8)));
typedef float f32x4  __attribute__((ext_vector_type(4)));

#define DEV static __device__ __forceinline__

DEV float bf2f(uint32_t u) { uint32_t v = u << 16; float f; __builtin_memcpy(&f, &v, 4); return f; }
DEV uint16_t f2bf(float f) {
  uint32_t u; __builtin_memcpy(&u, &f, 4);
  u = (u + 0x7fffu + ((u >> 16) & 1u)) >> 16;   // RNE
  return (uint16_t)u;
}

DEV void gl_lds16(const uint16_t* g, uint16_t* l) {
  __builtin_amdgcn_global_load_lds((const __attribute__((address_space(1))) uint32_t*)g,
                                   (__attribute__((address_space(3))) uint32_t*)l, 16, 0, 0);
}

// ---------------------------- weight conversion ----------------------------

__global__ __launch_bounds__(256) void cvt_bf16_k(const float* __restrict__ src,
                                                  uint16_t* __restrict__ dst, int n4) {
  const int t = blockIdx.x * 256 + threadIdx.x;
  if (t >= n4) return;
  const float4 v = ((const float4*)src)[t];
  ushort4 o; o.x = f2bf(v.x); o.y = f2bf(v.y); o.z = f2bf(v.z); o.w = f2bf(v.w);
  ((ushort4*)dst)[t] = o;
}

__global__ __launch_bounds__(256) void cvt_split_qk_k(const float* __restrict__ qw,
                                                      const float* __restrict__ kw,
                                                      uint16_t* __restrict__ hi,
                                                      uint16_t* __restrict__ lo) {
  const int t = blockIdx.x * 256 + threadIdx.x;    // 2048*256 float4s
  const int row = t >> 8, c4 = t & 255;
  const float* src = (row < 1024) ? (qw + (size_t)row * 1024)
                                  : (kw + (size_t)(row - 1024) * 1024);
  const float4 v = ((const float4*)src)[c4];
  ushort4 h, l;
  h.x = f2bf(v.x); l.x = f2bf(v.x - bf2f(h.x));
  h.y = f2bf(v.y); l.y = f2bf(v.y - bf2f(h.y));
  h.z = f2bf(v.z); l.z = f2bf(v.z - bf2f(h.z));
  h.w = f2bf(v.w); l.w = f2bf(v.w - bf2f(h.w));
  ((ushort4*)hi)[t] = h; ((ushort4*)lo)[t] = l;
}

// -------------------------------- rmsnorm ----------------------------------

template <bool SPLIT>
__global__ __launch_bounds__(256) void rmsnorm_k(const float* __restrict__ xin,
                                                 const float* __restrict__ g,
                                                 uint16_t* __restrict__ hi,
                                                 uint16_t* __restrict__ lo) {
  const int row = blockIdx.x, t = threadIdx.x;
  const float4 v = ((const float4*)(xin + (size_t)row * 1024))[t];
  float ss = v.x * v.x + v.y * v.y + v.z * v.z + v.w * v.w;
#pragma unroll
  for (int m = 1; m < 64; m <<= 1) ss += __shfl_xor(ss, m);
  __shared__ float red[4];
  if ((t & 63) == 0) red[t >> 6] = ss;
  __syncthreads();
  const float rinv = rsqrtf((red[0] + red[1] + red[2] + red[3]) * (1.0f / 1024.0f) + 1e-5f);
  const float4 gv = ((const float4*)g)[t];
  float y[4] = { v.x * rinv * gv.x, v.y * rinv * gv.y, v.z * rinv * gv.z, v.w * rinv * gv.w };
  ushort4 h; h.x = f2bf(y[0]); h.y = f2bf(y[1]); h.z = f2bf(y[2]); h.w = f2bf(y[3]);
  ((ushort4*)(hi + (size_t)row * 1024))[t] = h;
  if constexpr (SPLIT) {
    ushort4 l;
    l.x = f2bf(y[0] - bf2f(h.x)); l.y = f2bf(y[1] - bf2f(h.y));
    l.z = f2bf(y[2] - bf2f(h.z)); l.w = f2bf(y[3] - bf2f(h.w));
    ((ushort4*)(lo + (size_t)row * 1024))[t] = l;
  }
}

// ------------------------ GEMM  C[M,N] = A[M,K] @ B[N,K]^T ------------------
// 128x128 tile, BK=64, 4 waves (2x2), 16x16x32 bf16 MFMA.
// LDS tiles XOR-swizzled: slot [r][g] holds global colgrp g^(r&7).

template <int OUT>   // 0: bf16 out; 1: f32 out + residual add
__global__ __launch_bounds__(256) void gemm_bt_k(const uint16_t* __restrict__ A,
                                                 const uint16_t* __restrict__ B,
                                                 void* __restrict__ C,
                                                 const float* __restrict__ resid,
                                                 int N, int K) {
  __shared__ __align__(16) uint16_t As[128 * 64];
  __shared__ __align__(16) uint16_t Bs[128 * 64];
  const int t = threadIdx.x, w = t >> 6, lane = t & 63, m16 = lane & 15, quad = lane >> 4;
  const int wm = (w >> 1) * 64, wn = (w & 1) * 64;
  const int mBase = blockIdx.y * 128, nBase = blockIdx.x * 128;
  f32x4 acc[4][4];
  const f32x4 vz = {0.f, 0.f, 0.f, 0.f};
#pragma unroll
  for (int i = 0; i < 4; ++i)
#pragma unroll
    for (int j = 0; j < 4; ++j) acc[i][j] = vz;
  const int r_ = t >> 3, g_ = t & 7, sg = g_ ^ (r_ & 7);   // (it*32) % 8 == 0
  const uint16_t* ag = A + (size_t)(mBase + r_) * K + sg * 8;
  const uint16_t* bg = B + (size_t)(nBase + r_) * K + sg * 8;
  for (int k0 = 0; k0 < K; k0 += 64) {
#pragma unroll
    for (int it = 0; it < 4; ++it) {
      gl_lds16(ag + (size_t)(it * 32) * K + k0, As + it * 2048 + t * 8);
      gl_lds16(bg + (size_t)(it * 32) * K + k0, Bs + it * 2048 + t * 8);
    }
    __syncthreads();
#pragma unroll
    for (int ks = 0; ks < 2; ++ks) {
      bf16x8 af[4], bf4[4];
      const int cg = ks * 4 + quad;
#pragma unroll
      for (int i = 0; i < 4; ++i) {
        const int rA = wm + i * 16 + m16;
        af[i] = *(const bf16x8*)(As + rA * 64 + ((cg ^ (rA & 7)) * 8));
        const int rB = wn + i * 16 + m16;
        bf4[i] = *(const bf16x8*)(Bs + rB * 64 + ((cg ^ (rB & 7)) * 8));
      }
#pragma unroll
      for (int i = 0; i < 4; ++i)
#pragma unroll
        for (int j = 0; j < 4; ++j)
          acc[i][j] = __builtin_amdgcn_mfma_f32_16x16x32_bf16(af[i], bf4[j], acc[i][j], 0, 0, 0);
    }
    __syncthreads();
  }
#pragma unroll
  for (int i = 0; i < 4; ++i) {
    const int row0 = mBase + wm + i * 16 + quad * 4;
#pragma unroll
    for (int j = 0; j < 4; ++j) {
      const int col = nBase + wn + j * 16 + m16;
#pragma unroll
      for (int r = 0; r < 4; ++r) {
        const size_t idx = (size_t)(row0 + r) * N + col;
        const float v = acc[i][j][r];
        if constexpr (OUT == 1) ((float*)C)[idx] = v + resid[idx];
        else                    ((uint16_t*)C)[idx] = f2bf(v);
      }
    }
  }
}

// ---------------- split-precision GEMM (Q/K projection), BK=32 -------------
// acc += Ahi*Bhi + Ahi*Blo + Alo*Bhi  (drops lo*lo: ~2^-18 relative)

__global__ __launch_bounds__(256) void gemm_bt_split_k(
    const uint16_t* __restrict__ Ahi, const uint16_t* __restrict__ Alo,
    const uint16_t* __restrict__ Bhi, const uint16_t* __restrict__ Blo,
    uint16_t* __restrict__ Chi, uint16_t* __restrict__ Clo, int N, int K) {
  __shared__ __align__(16) uint16_t Ah[128 * 32];
  __shared__ __align__(16) uint16_t Al[128 * 32];
  __shared__ __align__(16) uint16_t Bh[128 * 32];
  __shared__ __align__(16) uint16_t Bl[128 * 32];
  const int t = threadIdx.x, w = t >> 6, lane = t & 63, m16 = lane & 15, quad = lane >> 4;
  const int wm = (w >> 1) * 64, wn = (w & 1) * 64;
  const int mBase = blockIdx.y * 128, nBase = blockIdx.x * 128;
  f32x4 acc[4][4];
  const f32x4 vz = {0.f, 0.f, 0.f, 0.f};
#pragma unroll
  for (int i = 0; i < 4; ++i)
#pragma unroll
    for (int j = 0; j < 4; ++j) acc[i][j] = vz;
  const int r_ = t >> 2, g_ = t & 3, sg = g_ ^ (r_ & 3);   // (it*64) % 4 == 0
  const uint16_t* agh = Ahi + (size_t)(mBase + r_) * K + sg * 8;
  const uint16_t* agl = Alo + (size_t)(mBase + r_) * K + sg * 8;
  const uint16_t* bgh = Bhi + (size_t)(nBase + r_) * K + sg * 8;
  const uint16_t* bgl = Blo + (size_t)(nBase + r_) * K + sg * 8;
  for (int k0 = 0; k0 < K; k0 += 32) {
#pragma unroll
    for (int it = 0; it < 2; ++it) {
      gl_lds16(agh + (size_t)(it * 64) * K + k0, Ah + it * 2048 + t * 8);
      gl_lds16(agl + (size_t)(it * 64) * K + k0, Al + it * 2048 + t * 8);
      gl_lds16(bgh + (size_t)(it * 64) * K + k0, Bh + it * 2048 + t * 8);
      gl_lds16(bgl + (size_t)(it * 64) * K + k0, Bl + it * 2048 + t * 8);
    }
    __syncthreads();
    bf16x8 ah[4], al[4], bh4[4], bl4[4];
#pragma unroll
    for (int i = 0; i < 4; ++i) {
      const int rA = wm + i * 16 + m16;
      const int offA = rA * 32 + ((quad ^ (rA & 3)) * 8);
      ah[i] = *(const bf16x8*)(Ah + offA);
      al[i] = *(const bf16x8*)(Al + offA);
      const int rB = wn + i * 16 + m16;
      const int offB = rB * 32 + ((quad ^ (rB & 3)) * 8);
      bh4[i] = *(const bf16x8*)(Bh + offB);
      bl4[i] = *(const bf16x8*)(Bl + offB);
    }
#pragma unroll
    for (int i = 0; i < 4; ++i)
#pragma unroll
      for (int j = 0; j < 4; ++j) {
        acc[i][j] = __builtin_amdgcn_mfma_f32_16x16x32_bf16(ah[i], bh4[j], acc[i][j], 0, 0, 0);
        acc[i][j] = __builtin_amdgcn_mfma_f32_16x16x32_bf16(ah[i], bl4[j], acc[i][j], 0, 0, 0);
        acc[i][j] = __builtin_amdgcn_mfma_f32_16x16x32_bf16(al[i], bh4[j], acc[i][j], 0, 0, 0);
      }
    __syncthreads();
  }
#pragma unroll
  for (int i = 0; i < 4; ++i) {
    const int row0 = mBase + wm + i * 16 + quad * 4;
#pragma unroll
    for (int j = 0; j < 4; ++j) {
      const int col = nBase + wn + j * 16 + m16;
#pragma unroll
      for (int r = 0; r < 4; ++r) {
        const size_t idx = (size_t)(row0 + r) * N + col;
        const float v = acc[i][j][r];
        const uint16_t hh = f2bf(v);
        Chi[idx] = hh;
        Clo[idx] = f2bf(v - bf2f(hh));
      }
    }
  }
}

// ---------------------------------- RoPE -----------------------------------
// In-place on split QK buffer [8192][2048] (cols 0..1023 Q, 1024..2047 K).

__global__ __launch_bounds__(256) void rope_k(uint16_t* __restrict__ qkh,
                                              uint16_t* __restrict__ qkl,
                                              const int* __restrict__ pos) {
  const int t = blockIdx.x * 256 + threadIdx.x;   // 8192*1024 pairs
  const int row = t >> 10, p = t & 1023;
  const int which = p >> 9, hp = p & 511, h = hp >> 5, d2 = hp & 31;
  const size_t idx = (size_t)row * 2048 + which * 1024 + h * 64 + d2 * 2;
  const uint32_t ph = *(const uint32_t*)(qkh + idx);
  const uint32_t pl = *(const uint32_t*)(qkl + idx);
  const float xe = bf2f(ph & 0xffffu) + bf2f(pl & 0xffffu);
  const float xo = bf2f(ph >> 16) + bf2f(pl >> 16);
  // inv_freq = 10000^(-d2/32) = exp2(-d2 * log2(10000)/32)
  const float inv_freq = exp2f((float)d2 * -0.41524101186092029f);
  const float fr = (float)pos[row & 2047] * inv_freq;
  float sn, cs; sincosf(fr, &sn, &cs);
  const float re = xe * cs - xo * sn;
  const float ro = xe * sn + xo * cs;
  const uint16_t reh = f2bf(re), roh = f2bf(ro);
  const uint16_t rel = f2bf(re - bf2f(reh)), rol = f2bf(ro - bf2f(roh));
  *(uint32_t*)(qkh + idx) = (uint32_t)reh | ((uint32_t)roh << 16);
  *(uint32_t*)(qkl + idx) = (uint32_t)rel | ((uint32_t)rol << 16);
}

// ------------------------- V transpose: [s][d] -> [d][s] --------------------

__global__ __launch_bounds__(256) void transpose_v_k(const uint16_t* __restrict__ V,
                                                     uint16_t* __restrict__ Vt) {
  __shared__ __align__(16) uint16_t tile[64][72];
  const int st = blockIdx.x, bh = blockIdx.y, b = bh >> 4, h = bh & 15;
  const int t = threadIdx.x;
  {
    const int sl = t >> 3, dg = t & 7;
#pragma unroll
    for (int it = 0; it < 2; ++it) {
      const int s = it * 32 + sl;
      const uint4 v = *(const uint4*)(V + (size_t)(b * 2048 + st * 64 + s) * 1024 + h * 64 + dg * 8);
      *(uint4*)(&tile[s][dg * 8]) = v;
    }
  }
  __syncthreads();
  {
    const int dl = t >> 3, sg2 = t & 7;
#pragma unroll
    for (int it = 0; it < 2; ++it) {
      const int d = it * 32 + dl;
      union { uint4 v; uint16_t u[8]; } pk;
#pragma unroll
      for (int r = 0; r < 8; ++r) pk.u[r] = tile[sg2 * 8 + r][d];
      *(uint4*)(Vt + (size_t)(bh * 64 + d) * 2048 + st * 64 + sg2 * 8) = pk.v;
    }
  }
}

// ----------------------- causal flash attention -----------------------------
// R7: double-buffered K/V LDS + counted vmcnt(6) prefetch; 2 raw s_barriers
// per KV-iter; wave-private P (no mid barrier); diag-only masking; exp2 fold.
// Grid (8,64); each block processes the q-tile PAIR (qt, 15-qt) = 34 KV-iters.

__global__ __launch_bounds__(256) void flash_k(const uint16_t* __restrict__ Qh,
                                               const uint16_t* __restrict__ Ql,
                                               const uint16_t* __restrict__ Vt,
                                               uint16_t* __restrict__ Hout) {
  __shared__ __align__(16) uint16_t Kh[2][64 * 64];
  __shared__ __align__(16) uint16_t Kl[2][64 * 64];
  __shared__ __align__(16) uint16_t Vs[2][64 * 64];
  __shared__ __align__(16) uint16_t P[4][32 * 72];

  const int bh = blockIdx.y, b = bh >> 4, h = bh & 15;
  const int t = threadIdx.x, w = t >> 6, lane = t & 63, m16 = lane & 15, quad = lane >> 4;

  const int r_ = t >> 3, g_ = t & 7, sgx = g_ ^ (r_ & 7);
  const uint16_t* khg = Qh + (size_t)(b * 2048 + r_) * 2048 + 1024 + h * 64 + sgx * 8;
  const uint16_t* klg = Ql + (size_t)(b * 2048 + r_) * 2048 + 1024 + h * 64 + sgx * 8;
  const uint16_t* vtg = Vt + (size_t)(bh * 64 + r_) * 2048 + sgx * 8;

  const float nscl = 0.18033688011112042f;   // log2(e)/8: fold 1/sqrt(64) + ln->log2

  for (int half = 0; half < 2; ++half) {
    const int qt = half ? (15 - (int)blockIdx.x) : (int)blockIdx.x;

    bf16x8 qh[2][2], ql[2][2];
#pragma unroll
    for (int i = 0; i < 2; ++i) {
      const int row = b * 2048 + qt * 128 + w * 32 + i * 16 + m16;
#pragma unroll
      for (int ks = 0; ks < 2; ++ks) {
        const size_t offq = (size_t)row * 2048 + h * 64 + ks * 32 + quad * 8;
        qh[i][ks] = *(const bf16x8*)(Qh + offq);
        ql[i][ks] = *(const bf16x8*)(Ql + offq);
      }
    }
    // Pin Q fragments: forces the compiler's vmcnt drain HERE, so inside the
    // loop the outstanding-VMEM count is exactly our 6 DMA loads per tile.
#pragma unroll
    for (int i = 0; i < 2; ++i)
#pragma unroll
      for (int ks = 0; ks < 2; ++ks)
        asm volatile("" : "+v"(qh[i][ks]), "+v"(ql[i][ks]));

    const int ktEnd = 2 * qt + 2;

    // prologue: stage tile 0 into buffer 0 (6 DMA loads in flight)
#pragma unroll
    for (int it = 0; it < 2; ++it) {
      gl_lds16(khg + (size_t)(it * 32) * 2048, &Kh[0][it * 2048 + t * 8]);
      gl_lds16(klg + (size_t)(it * 32) * 2048, &Kl[0][it * 2048 + t * 8]);
      gl_lds16(vtg + (size_t)(it * 32) * 2048, &Vs[0][it * 2048 + t * 8]);
    }

    float mr[2][4], lr[2][4];
    f32x4 o[2][4];
    const f32x4 vz = {0.f, 0.f, 0.f, 0.f};
#pragma unroll
    for (int i = 0; i < 2; ++i)
#pragma unroll
      for (int r = 0; r < 4; ++r) { mr[i][r] = -1e30f; lr[i][r] = 0.f; }
#pragma unroll
    for (int i = 0; i < 2; ++i)
#pragma unroll
      for (int n = 0; n < 4; ++n) o[i][n] = vz;

    for (int kt = 0; kt < ktEnd; ++kt) {
      const int cur = kt & 1, nxt = cur ^ 1;
      // guard: all waves finished READING buf[nxt] (its reads ended 2 iters
      // ago; every ds_read completes before its consuming MFMA, which
      // precedes this barrier in program order).
      __builtin_amdgcn_s_barrier();
      __builtin_amdgcn_sched_barrier(0);
      if (kt + 1 < ktEnd) {
        const int kn = kt + 1;
#pragma unroll
        for (int it = 0; it < 2; ++it) {
          gl_lds16(khg + (size_t)(kn * 64 + it * 32) * 2048, &Kh[nxt][it * 2048 + t * 8]);
          gl_lds16(klg + (size_t)(kn * 64 + it * 32) * 2048, &Kl[nxt][it * 2048 + t * 8]);
          gl_lds16(vtg + (size_t)(it * 32) * 2048 + kn * 64, &Vs[nxt][it * 2048 + t * 8]);
        }
        // drain tile kt's 6 loads; keep tile kt+1's 6 in flight (T4)
        asm volatile("s_waitcnt vmcnt(6)" ::: "memory");
      } else {
        asm volatile("s_waitcnt vmcnt(0)" ::: "memory");
      }
      __builtin_amdgcn_s_barrier();
      __builtin_amdgcn_sched_barrier(0);

      // ---- QK^T (3-pass hi/lo) on buf[cur] ----
      f32x4 sc[2][4];
#pragma unroll
      for (int i = 0; i < 2; ++i)
#pragma unroll
        for (int j = 0; j < 4; ++j) sc[i][j] = vz;
#pragma unroll
      for (int ks = 0; ks < 2; ++ks) {
        bf16x8 kfh[4], kfl[4];
        const int cg = ks * 4 + quad;
#pragma unroll
        for (int j = 0; j < 4; ++j) {
          const int rK = j * 16 + m16;
          const int offk = rK * 64 + ((cg ^ (rK & 7)) * 8);
          kfh[j] = *(const bf16x8*)(&Kh[cur][offk]);
          kfl[j] = *(const bf16x8*)(&Kl[cur][offk]);
        }
        __builtin_amdgcn_s_setprio(1);
#pragma unroll
        for (int i = 0; i < 2; ++i)
#pragma unroll
          for (int j = 0; j < 4; ++j) {
            sc[i][j] = __builtin_amdgcn_mfma_f32_16x16x32_bf16(qh[i][ks], kfh[j], sc[i][j], 0, 0, 0);
            sc[i][j] = __builtin_amdgcn_mfma_f32_16x16x32_bf16(qh[i][ks], kfl[j], sc[i][j], 0, 0, 0);
            sc[i][j] = __builtin_amdgcn_mfma_f32_16x16x32_bf16(ql[i][ks], kfh[j], sc[i][j], 0, 0, 0);
          }
        __builtin_amdgcn_s_setprio(0);
      }

      // ---- online softmax, raw-score domain (softmax is scale-invariant;
      //      P = exp2((s - m) * log2e/8), mask only on diagonal tiles) ----
#pragma unroll
      for (int i = 0; i < 2; ++i) {
        const bool needMask = (kt * 64 + 63) > (qt * 128 + w * 32 + i * 16);
#pragma unroll
        for (int r = 0; r < 4; ++r) {
          float mx = -1e30f;
          if (needMask) {
            const int qg = qt * 128 + w * 32 + i * 16 + quad * 4 + r;
#pragma unroll
            for (int j = 0; j < 4; ++j) {
              float v = sc[i][j][r];
              const int kg = kt * 64 + j * 16 + m16;
              if (kg > qg) v = -1e30f;
              sc[i][j][r] = v;
              mx = fmaxf(mx, v);
            }
          } else {
#pragma unroll
            for (int j = 0; j < 4; ++j) mx = fmaxf(mx, sc[i][j][r]);
          }
#pragma unroll
          for (int m = 1; m < 16; m <<= 1) mx = fmaxf(mx, __shfl_xor(mx, m));
          const float mnew = fmaxf(mr[i][r], mx);
          const float alpha = __builtin_amdgcn_exp2f((mr[i][r] - mnew) * nscl);
          mr[i][r] = mnew;
          const float nm = mnew * nscl;
          float ls = 0.f;
#pragma unroll
          for (int j = 0; j < 4; ++j) {
            const float pv = __builtin_amdgcn_exp2f(__builtin_fmaf(sc[i][j][r], nscl, -nm));
            sc[i][j][r] = pv;
            ls += pv;
          }
#pragma unroll
          for (int m = 1; m < 16; m <<= 1) ls += __shfl_xor(ls, m);
          lr[i][r] = lr[i][r] * alpha + ls;
#pragma unroll
          for (int n = 0; n < 4; ++n) o[i][n][r] *= alpha;
        }
#pragma unroll
        for (int j = 0; j < 4; ++j)
#pragma unroll
          for (int r = 0; r < 4; ++r)
            P[w][(i * 16 + quad * 4 + r) * 72 + j * 16 + m16] = f2bf(sc[i][j][r]);
      }
      // P[w] is wave-private: intra-wave ds_write->ds_read needs only the
      // compiler-inserted lgkmcnt, no cross-wave barrier.

#pragma unroll
      for (int ks2 = 0; ks2 < 2; ++ks2) {
        bf16x8 pf[2], vf[4];
#pragma unroll
        for (int i = 0; i < 2; ++i)
          pf[i] = *(const bf16x8*)(&P[w][(i * 16 + m16) * 72 + ks2 * 32 + quad * 8]);
        const int cg = ks2 * 4 + quad;
#pragma unroll
        for (int n = 0; n < 4; ++n) {
          const int rV = n * 16 + m16;
          vf[n] = *(const bf16x8*)(&Vs[cur][rV * 64 + ((cg ^ (rV & 7)) * 8)]);
        }
        __builtin_amdgcn_s_setprio(1);
#pragma unroll
        for (int i = 0; i < 2; ++i)
#pragma unroll
          for (int n = 0; n < 4; ++n)
            o[i][n] = __builtin_amdgcn_mfma_f32_16x16x32_bf16(pf[i], vf[n], o[i][n], 0, 0, 0);
        __builtin_amdgcn_s_setprio(0);
      }
    }

#pragma unroll
    for (int i = 0; i < 2; ++i)
#pragma unroll
      for (int r = 0; r < 4; ++r) {
        const float inv = 1.f / lr[i][r];
        const size_t row = (size_t)(b * 2048 + qt * 128 + w * 32 + i * 16 + quad * 4 + r);
#pragma unroll
        for (int n = 0; n < 4; ++n)
          Hout[row * 1024 + h * 64 + n * 16 + m16] = f2bf(o[i][n][r] * inv);
      }
    // full drain (vmcnt(0) incl. Hout stores) + barrier before the next half
    // re-stages buffer 0.
    __syncthreads();
  }
}

// --------------------------------- swiglu ----------------------------------

__global__ __launch_bounds__(256) void swiglu_k(uint16_t* __restrict__ a,
                                                const uint16_t* __restrict__ g, int n8) {
  const int t = blockIdx.x * 256 + threadIdx.x;
  if (t >= n8) return;
  union { uint4 v; uint16_t u[8]; } av, gv, hv;
  av.v = ((const uint4*)a)[t];
  gv.v = ((const uint4*)g)[t];
#pragma unroll
  for (int e = 0; e < 8; ++e) {
    const float x = bf2f(av.u[e]);
    const float gg = bf2f(gv.u[e]);
    const float sw = x / (1.f + __expf(-x));
    hv.u[e] = f2bf(sw * gg);
  }
  ((uint4*)a)[t] = hv.v;
}

// ------------------------------ orchestration -------------------------------

extern "C" void kernel_launch(void* const* d_in, const int* in_sizes, int n_in,
                              void* d_out, int out_size, void* d_ws, size_t ws_size,
                              hipStream_t stream) {
  (void)in_sizes; (void)n_in; (void)out_size; (void)ws_size;
  const float* x   = (const float*)d_in[0];
  const int*   pos = (const int*)  d_in[1];
  const float* q_w = (const float*)d_in[2];
  const float* k_w = (const float*)d_in[3];
  const float* v_w = (const float*)d_in[4];
  const float* o_w = (const float*)d_in[5];
  const float* g1  = (const float*)d_in[6];
  const float* g2  = (const float*)d_in[7];
  const float* w1  = (const float*)d_in[8];
  const float* w2  = (const float*)d_in[9];
  const float* w3  = (const float*)d_in[10];

  char* ws = (char*)d_ws;
  uint16_t* wqk_hi = (uint16_t*)(ws + 0);
  uint16_t* wqk_lo = (uint16_t*)(ws + 4194304);
  uint16_t* wv     = (uint16_t*)(ws + 8388608);
  uint16_t* wo     = (uint16_t*)(ws + 10485760);
  uint16_t* w1b    = (uint16_t*)(ws + 12582912);
  uint16_t* w3b    = (uint16_t*)(ws + 20971520);
  uint16_t* w2b    = (uint16_t*)(ws + 29360128);
  uint16_t* xn_hi  = (uint16_t*)(ws + 37748736);
  uint16_t* xn_lo  = (uint16_t*)(ws + 54525952);
  uint16_t* vbuf   = (uint16_t*)(ws + 71303168);
  uint16_t* vt     = (uint16_t*)(ws + 88080384);
  uint16_t* qk_hi  = (uint16_t*)(ws + 104857600);
  uint16_t* qk_lo  = (uint16_t*)(ws + 138412032);
  uint16_t* hbuf   = (uint16_t*)(ws + 171966464);
  float*    ores   = (float*)   (ws + 188743680);
  uint16_t* on2    = (uint16_t*)(ws + 222298112);
  // overlays (regions dead by the time these are written):
  uint16_t* abuf   = (uint16_t*)(ws + 104857600);  // over qk_hi+qk_lo (67.1 MB)
  uint16_t* gbuf   = (uint16_t*)(ws + 37748736);   // over xn_hi..vt   (67.1 MB)
  // total ws required: 239,075,328 bytes

  cvt_split_qk_k<<<2048, 256, 0, stream>>>(q_w, k_w, wqk_hi, wqk_lo);
  cvt_bf16_k<<<1024, 256, 0, stream>>>(v_w, wv, 262144);
  cvt_bf16_k<<<1024, 256, 0, stream>>>(o_w, wo, 262144);
  cvt_bf16_k<<<4096, 256, 0, stream>>>(w1, w1b, 1048576);
  cvt_bf16_k<<<4096, 256, 0, stream>>>(w3, w3b, 1048576);
  cvt_bf16_k<<<4096, 256, 0, stream>>>(w2, w2b, 1048576);

  rmsnorm_k<true><<<8192, 256, 0, stream>>>(x, g1, xn_hi, xn_lo);

  gemm_bt_split_k<<<dim3(16, 64), 256, 0, stream>>>(xn_hi, xn_lo, wqk_hi, wqk_lo,
                                                    qk_hi, qk_lo, 2048, 1024);
  gemm_bt_k<0><<<dim3(8, 64), 256, 0, stream>>>(xn_hi, wv, (void*)vbuf, nullptr, 1024, 1024);

  rope_k<<<32768, 256, 0, stream>>>(qk_hi, qk_lo, pos);
  transpose_v_k<<<dim3(32, 64), 256, 0, stream>>>(vbuf, vt);

  flash_k<<<dim3(8, 64), 256, 0, stream>>>(qk_hi, qk_lo, vt, hbuf);

  gemm_bt_k<1><<<dim3(8, 64), 256, 0, stream>>>(hbuf, wo, (void*)ores, x, 1024, 1024);

  rmsnorm_k<false><<<8192, 256, 0, stream>>>(ores, g2, on2, nullptr);

  gemm_bt_k<0><<<dim3(32, 64), 256, 0, stream>>>(on2, w1b, (void*)abuf, nullptr, 4096, 1024);
  gemm_bt_k<0><<<dim3(32, 64), 256, 0, stream>>>(on2, w3b, (void*)gbuf, nullptr, 4096, 1024);
  swiglu_k<<<16384, 256, 0, stream>>>(abuf, gbuf, 4194304);

  gemm_bt_k<1><<<dim3(8, 64), 256, 0, stream>>>(abuf, w2b, d_out, ores, 1024, 4096);
}

// Round 2
// 807.621 us; speedup vs baseline: 1.0799x; 1.0483x over previous
//
#include <hip/hip_runtime.h>
#include <stdint.h>

// ---------------------------------------------------------------------------
// TransformerBlock: rmsnorm -> QKV -> RoPE -> causal flash attn -> +x ->
//                   rmsnorm -> swiglu FFN -> +O
// bf16 MFMA everywhere; Q/K path uses hi/lo bf16 split (3-pass MFMA).
// R8: (a) NEW gemm256_k - 256x256 tile, BK=64, 8 waves, 8-phase-style schedule
//     (4 phases/K-tile, 2 K-tiles per LDS dbuf cycle): stage 2 TILES AHEAD at
//     1 half-tile (2 gl_lds) per phase; ONE counted s_waitcnt vmcnt(6) per
//     K-tile (T3/T4); setprio(1) around 16-MFMA clusters (T5). Hand-verified
//     half-tile retire/stage schedule:
//       stream: ph0->Bh1(T+1), ph1->Ah1(T+1), ph2->Bh0(T+2), ph3->Ah0(T+2)
//       B-halves retire after ph1, A-halves after ph2 (reg-held frags);
//       vmcnt(6) at ph0 keeps newest 3 halves, drains all of tile T. Used for
//     w1/w3 FFN GEMMs (512 blocks, full occupancy shapes).
//     (b) swiglu fused into w3 epilogue (OUT=2) - swiglu_k deleted (~16us).
//     (c) V^T via operand swap (Vt = Wv @ Xn^T) - transpose_v_k deleted.
// R7: flash_k K/V LDS dbuf + counted vmcnt(6), raw s_barriers, wave-private P,
//     diag-only masking, exp2 fold, setprio. (240 -> 182 us, verified.)
// R6: flash grid (8,64), q-tile PAIR (qt, 15-qt) = 34 KV-iters per block.
// ---------------------------------------------------------------------------

typedef short bf16x8 __attribute__((ext_vector_type(8)));
typedef float f32x4  __attribute__((ext_vector_type(4)));

#define DEV static __device__ __forceinline__

DEV float bf2f(uint32_t u) { uint32_t v = u << 16; float f; __builtin_memcpy(&f, &v, 4); return f; }
DEV uint16_t f2bf(float f) {
  uint32_t u; __builtin_memcpy(&u, &f, 4);
  u = (u + 0x7fffu + ((u >> 16) & 1u)) >> 16;   // RNE
  return (uint16_t)u;
}

DEV void gl_lds16(const uint16_t* g, uint16_t* l) {
  __builtin_amdgcn_global_load_lds((const __attribute__((address_space(1))) uint32_t*)g,
                                   (__attribute__((address_space(3))) uint32_t*)l, 16, 0, 0);
}

// ---------------------------- weight conversion ----------------------------

__global__ __launch_bounds__(256) void cvt_bf16_k(const float* __restrict__ src,
                                                  uint16_t* __restrict__ dst, int n4) {
  const int t = blockIdx.x * 256 + threadIdx.x;
  if (t >= n4) return;
  const float4 v = ((const float4*)src)[t];
  ushort4 o; o.x = f2bf(v.x); o.y = f2bf(v.y); o.z = f2bf(v.z); o.w = f2bf(v.w);
  ((ushort4*)dst)[t] = o;
}

__global__ __launch_bounds__(256) void cvt_split_qk_k(const float* __restrict__ qw,
                                                      const float* __restrict__ kw,
                                                      uint16_t* __restrict__ hi,
                                                      uint16_t* __restrict__ lo) {
  const int t = blockIdx.x * 256 + threadIdx.x;    // 2048*256 float4s
  const int row = t >> 8, c4 = t & 255;
  const float* src = (row < 1024) ? (qw + (size_t)row * 1024)
                                  : (kw + (size_t)(row - 1024) * 1024);
  const float4 v = ((const float4*)src)[c4];
  ushort4 h, l;
  h.x = f2bf(v.x); l.x = f2bf(v.x - bf2f(h.x));
  h.y = f2bf(v.y); l.y = f2bf(v.y - bf2f(h.y));
  h.z = f2bf(v.z); l.z = f2bf(v.z - bf2f(h.z));
  h.w = f2bf(v.w); l.w = f2bf(v.w - bf2f(h.w));
  ((ushort4*)hi)[t] = h; ((ushort4*)lo)[t] = l;
}

// -------------------------------- rmsnorm ----------------------------------

template <bool SPLIT>
__global__ __launch_bounds__(256) void rmsnorm_k(const float* __restrict__ xin,
                                                 const float* __restrict__ g,
                                                 uint16_t* __restrict__ hi,
                                                 uint16_t* __restrict__ lo) {
  const int row = blockIdx.x, t = threadIdx.x;
  const float4 v = ((const float4*)(xin + (size_t)row * 1024))[t];
  float ss = v.x * v.x + v.y * v.y + v.z * v.z + v.w * v.w;
#pragma unroll
  for (int m = 1; m < 64; m <<= 1) ss += __shfl_xor(ss, m);
  __shared__ float red[4];
  if ((t & 63) == 0) red[t >> 6] = ss;
  __syncthreads();
  const float rinv = rsqrtf((red[0] + red[1] + red[2] + red[3]) * (1.0f / 1024.0f) + 1e-5f);
  const float4 gv = ((const float4*)g)[t];
  float y[4] = { v.x * rinv * gv.x, v.y * rinv * gv.y, v.z * rinv * gv.z, v.w * rinv * gv.w };
  ushort4 h; h.x = f2bf(y[0]); h.y = f2bf(y[1]); h.z = f2bf(y[2]); h.w = f2bf(y[3]);
  ((ushort4*)(hi + (size_t)row * 1024))[t] = h;
  if constexpr (SPLIT) {
    ushort4 l;
    l.x = f2bf(y[0] - bf2f(h.x)); l.y = f2bf(y[1] - bf2f(h.y));
    l.z = f2bf(y[2] - bf2f(h.z)); l.w = f2bf(y[3] - bf2f(h.w));
    ((ushort4*)(lo + (size_t)row * 1024))[t] = l;
  }
}

// ------------------------ GEMM  C[M,N] = A[M,K] @ B[N,K]^T ------------------
// 128x128 tile, BK=64, 4 waves (2x2), 16x16x32 bf16 MFMA.
// LDS tiles XOR-swizzled: slot [r][g] holds global colgrp g^(r&7).

template <int OUT>   // 0: bf16 out; 1: f32 out + residual add
__global__ __launch_bounds__(256) void gemm_bt_k(const uint16_t* __restrict__ A,
                                                 const uint16_t* __restrict__ B,
                                                 void* __restrict__ C,
                                                 const float* __restrict__ resid,
                                                 int N, int K) {
  __shared__ __align__(16) uint16_t As[128 * 64];
  __shared__ __align__(16) uint16_t Bs[128 * 64];
  const int t = threadIdx.x, w = t >> 6, lane = t & 63, m16 = lane & 15, quad = lane >> 4;
  const int wm = (w >> 1) * 64, wn = (w & 1) * 64;
  const int mBase = blockIdx.y * 128, nBase = blockIdx.x * 128;
  f32x4 acc[4][4];
  const f32x4 vz = {0.f, 0.f, 0.f, 0.f};
#pragma unroll
  for (int i = 0; i < 4; ++i)
#pragma unroll
    for (int j = 0; j < 4; ++j) acc[i][j] = vz;
  const int r_ = t >> 3, g_ = t & 7, sg = g_ ^ (r_ & 7);   // (it*32) % 8 == 0
  const uint16_t* ag = A + (size_t)(mBase + r_) * K + sg * 8;
  const uint16_t* bg = B + (size_t)(nBase + r_) * K + sg * 8;
  for (int k0 = 0; k0 < K; k0 += 64) {
#pragma unroll
    for (int it = 0; it < 4; ++it) {
      gl_lds16(ag + (size_t)(it * 32) * K + k0, As + it * 2048 + t * 8);
      gl_lds16(bg + (size_t)(it * 32) * K + k0, Bs + it * 2048 + t * 8);
    }
    __syncthreads();
#pragma unroll
    for (int ks = 0; ks < 2; ++ks) {
      bf16x8 af[4], bf4[4];
      const int cg = ks * 4 + quad;
#pragma unroll
      for (int i = 0; i < 4; ++i) {
        const int rA = wm + i * 16 + m16;
        af[i] = *(const bf16x8*)(As + rA * 64 + ((cg ^ (rA & 7)) * 8));
        const int rB = wn + i * 16 + m16;
        bf4[i] = *(const bf16x8*)(Bs + rB * 64 + ((cg ^ (rB & 7)) * 8));
      }
#pragma unroll
      for (int i = 0; i < 4; ++i)
#pragma unroll
        for (int j = 0; j < 4; ++j)
          acc[i][j] = __builtin_amdgcn_mfma_f32_16x16x32_bf16(af[i], bf4[j], acc[i][j], 0, 0, 0);
    }
    __syncthreads();
  }
#pragma unroll
  for (int i = 0; i < 4; ++i) {
    const int row0 = mBase + wm + i * 16 + quad * 4;
#pragma unroll
    for (int j = 0; j < 4; ++j) {
      const int col = nBase + wn + j * 16 + m16;
#pragma unroll
      for (int r = 0; r < 4; ++r) {
        const size_t idx = (size_t)(row0 + r) * N + col;
        const float v = acc[i][j][r];
        if constexpr (OUT == 1) ((float*)C)[idx] = v + resid[idx];
        else                    ((uint16_t*)C)[idx] = f2bf(v);
      }
    }
  }
}

// -------------- 256x256 8-phase GEMM  C[M,N] = A[M,K] @ B[N,K]^T ------------
// BK=64, 512 thr = 8 waves (2M x 4N), per-wave 128x64 out = acc[8][4].
// LDS: A/B double-buffered 256x64 each = 128 KiB. Stage 2 tiles ahead,
// 1 half-tile (2 gl_lds) per phase; vmcnt(6) once per K-tile (phase 0).
// Safety (hand-verified):
//  - B-half LDS regions last read at ph1, A-halves at ph2 (frags reg-held);
//    stage slots ph2/ph3 (into cur buf) and ph0/ph1 (into other buf) only
//    touch retired regions, sealed by the per-phase closing barrier.
//  - vmcnt(6) at ph0 keeps newest 3 halves (T+1/T+2 stream), drains all 4
//    halves of tile T before the post-vmcnt barrier + ds_reads.

template <int OUT>   // 0: bf16 store; 2: bf16 store of silu(aux)*acc (fused swiglu)
__global__ __launch_bounds__(512, 2) void gemm256_k(const uint16_t* __restrict__ A,
                                                    const uint16_t* __restrict__ B,
                                                    uint16_t* __restrict__ C,
                                                    const uint16_t* __restrict__ aux,
                                                    int N, int K) {
  __shared__ __align__(16) uint16_t As[2][256 * 64];
  __shared__ __align__(16) uint16_t Bs[2][256 * 64];
  const int t = threadIdx.x, w = t >> 6, lane = t & 63, m16 = lane & 15, quad = lane >> 4;
  const int wm = (w >> 2) * 128, wn = (w & 3) * 64;
  const int mBase = blockIdx.y * 256, nBase = blockIdx.x * 256;
  const int NT = K >> 6;

  f32x4 acc[8][4];
  const f32x4 vz = {0.f, 0.f, 0.f, 0.f};
#pragma unroll
  for (int i = 0; i < 8; ++i)
#pragma unroll
    for (int j = 0; j < 4; ++j) acc[i][j] = vz;

  const int r_ = t >> 3, g_ = t & 7, sg = g_ ^ (r_ & 7);   // 64-row chunks keep (row&7)
  const uint16_t* ag = A + (size_t)(mBase + r_) * K + sg * 8;
  const uint16_t* bg = B + (size_t)(nBase + r_) * K + sg * 8;

#define STG_A(kt, h)                                                         \
  if ((kt) < NT) {                                                           \
    uint16_t* d0 = &As[(kt) & 1][(h) * 8192 + t * 8];                        \
    const uint16_t* s0 = ag + (size_t)((h) * 128) * K + (kt) * 64;           \
    gl_lds16(s0, d0);                                                        \
    gl_lds16(s0 + (size_t)64 * K, d0 + 4096);                                \
  }
#define STG_B(kt, h)                                                         \
  if ((kt) < NT) {                                                           \
    uint16_t* d0 = &Bs[(kt) & 1][(h) * 8192 + t * 8];                        \
    const uint16_t* s0 = bg + (size_t)((h) * 128) * K + (kt) * 64;           \
    gl_lds16(s0, d0);                                                        \
    gl_lds16(s0 + (size_t)64 * K, d0 + 4096);                                \
  }

  // prologue: tile0 fully + tile1's Bh0/Ah0 (oldest-first for vmcnt math)
  STG_B(0, 0); STG_B(0, 1); STG_A(0, 0); STG_A(0, 1);
  STG_B(1, 0); STG_A(1, 0);

  for (int T = 0; T < NT; ++T) {
    const int c = T & 1;
    const uint16_t* Ac = As[c];
    const uint16_t* Bc = Bs[c];
    bf16x8 af[4][2], b0[2][2], b1[2][2];

    // ---------------- ph0: quadrant (mq0, nq0) ----------------
    STG_B(T + 1, 1);
    if (T == NT - 1) { asm volatile("s_waitcnt vmcnt(0)" ::: "memory"); }
    else             { asm volatile("s_waitcnt vmcnt(6)" ::: "memory"); }
    __builtin_amdgcn_s_barrier();
    __builtin_amdgcn_sched_barrier(0);
#pragma unroll
    for (int i = 0; i < 4; ++i) {
      const int rA = wm + i * 16 + m16;
#pragma unroll
      for (int ks = 0; ks < 2; ++ks)
        af[i][ks] = *(const bf16x8*)(Ac + rA * 64 + (((ks * 4 + quad) ^ (rA & 7)) * 8));
    }
#pragma unroll
    for (int j = 0; j < 2; ++j) {
      const int rB = wn + j * 16 + m16;
#pragma unroll
      for (int ks = 0; ks < 2; ++ks)
        b0[j][ks] = *(const bf16x8*)(Bc + rB * 64 + (((ks * 4 + quad) ^ (rB & 7)) * 8));
    }
    __builtin_amdgcn_s_setprio(1);
#pragma unroll
    for (int ks = 0; ks < 2; ++ks)
#pragma unroll
      for (int i = 0; i < 4; ++i)
#pragma unroll
        for (int j = 0; j < 2; ++j)
          acc[i][j] = __builtin_amdgcn_mfma_f32_16x16x32_bf16(af[i][ks], b0[j][ks], acc[i][j], 0, 0, 0);
    __builtin_amdgcn_s_setprio(0);
    __builtin_amdgcn_s_barrier();

    // ---------------- ph1: (mq0, nq1) ----------------
    STG_A(T + 1, 1);
#pragma unroll
    for (int j = 0; j < 2; ++j) {
      const int rB = wn + (2 + j) * 16 + m16;
#pragma unroll
      for (int ks = 0; ks < 2; ++ks)
        b1[j][ks] = *(const bf16x8*)(Bc + rB * 64 + (((ks * 4 + quad) ^ (rB & 7)) * 8));
    }
    __builtin_amdgcn_s_setprio(1);
#pragma unroll
    for (int ks = 0; ks < 2; ++ks)
#pragma unroll
      for (int i = 0; i < 4; ++i)
#pragma unroll
        for (int j = 0; j < 2; ++j)
          acc[i][2 + j] = __builtin_amdgcn_mfma_f32_16x16x32_bf16(af[i][ks], b1[j][ks], acc[i][2 + j], 0, 0, 0);
    __builtin_amdgcn_s_setprio(0);
    __builtin_amdgcn_s_barrier();

    // ---------------- ph2: (mq1, nq0) ----------------
    STG_B(T + 2, 0);
#pragma unroll
    for (int i = 0; i < 4; ++i) {
      const int rA = wm + 64 + i * 16 + m16;
#pragma unroll
      for (int ks = 0; ks < 2; ++ks)
        af[i][ks] = *(const bf16x8*)(Ac + rA * 64 + (((ks * 4 + quad) ^ (rA & 7)) * 8));
    }
    __builtin_amdgcn_s_setprio(1);
#pragma unroll
    for (int ks = 0; ks < 2; ++ks)
#pragma unroll
      for (int i = 0; i < 4; ++i)
#pragma unroll
        for (int j = 0; j < 2; ++j)
          acc[4 + i][j] = __builtin_amdgcn_mfma_f32_16x16x32_bf16(af[i][ks], b0[j][ks], acc[4 + i][j], 0, 0, 0);
    __builtin_amdgcn_s_setprio(0);
    __builtin_amdgcn_s_barrier();

    // ---------------- ph3: (mq1, nq1) ----------------
    STG_A(T + 2, 0);
    __builtin_amdgcn_s_setprio(1);
#pragma unroll
    for (int ks = 0; ks < 2; ++ks)
#pragma unroll
      for (int i = 0; i < 4; ++i)
#pragma unroll
        for (int j = 0; j < 2; ++j)
          acc[4 + i][2 + j] = __builtin_amdgcn_mfma_f32_16x16x32_bf16(af[i][ks], b1[j][ks], acc[4 + i][2 + j], 0, 0, 0);
    __builtin_amdgcn_s_setprio(0);
    __builtin_amdgcn_s_barrier();
  }
#undef STG_A
#undef STG_B

#pragma unroll
  for (int i = 0; i < 8; ++i) {
    const int row0 = mBase + wm + i * 16 + quad * 4;
#pragma unroll
    for (int j = 0; j < 4; ++j) {
      const int col = nBase + wn + j * 16 + m16;
#pragma unroll
      for (int r = 0; r < 4; ++r) {
        const size_t idx = (size_t)(row0 + r) * N + col;
        const float v = acc[i][j][r];
        if constexpr (OUT == 2) {
          const float a = bf2f(aux[idx]);
          const float sw = a / (1.f + __expf(-a));
          C[idx] = f2bf(sw * v);
        } else {
          C[idx] = f2bf(v);
        }
      }
    }
  }
}

// ---------------- split-precision GEMM (Q/K projection), BK=32 -------------
// acc += Ahi*Bhi + Ahi*Blo + Alo*Bhi  (drops lo*lo: ~2^-18 relative)

__global__ __launch_bounds__(256) void gemm_bt_split_k(
    const uint16_t* __restrict__ Ahi, const uint16_t* __restrict__ Alo,
    const uint16_t* __restrict__ Bhi, const uint16_t* __restrict__ Blo,
    uint16_t* __restrict__ Chi, uint16_t* __restrict__ Clo, int N, int K) {
  __shared__ __align__(16) uint16_t Ah[128 * 32];
  __shared__ __align__(16) uint16_t Al[128 * 32];
  __shared__ __align__(16) uint16_t Bh[128 * 32];
  __shared__ __align__(16) uint16_t Bl[128 * 32];
  const int t = threadIdx.x, w = t >> 6, lane = t & 63, m16 = lane & 15, quad = lane >> 4;
  const int wm = (w >> 1) * 64, wn = (w & 1) * 64;
  const int mBase = blockIdx.y * 128, nBase = blockIdx.x * 128;
  f32x4 acc[4][4];
  const f32x4 vz = {0.f, 0.f, 0.f, 0.f};
#pragma unroll
  for (int i = 0; i < 4; ++i)
#pragma unroll
    for (int j = 0; j < 4; ++j) acc[i][j] = vz;
  const int r_ = t >> 2, g_ = t & 3, sg = g_ ^ (r_ & 3);   // (it*64) % 4 == 0
  const uint16_t* agh = Ahi + (size_t)(mBase + r_) * K + sg * 8;
  const uint16_t* agl = Alo + (size_t)(mBase + r_) * K + sg * 8;
  const uint16_t* bgh = Bhi + (size_t)(nBase + r_) * K + sg * 8;
  const uint16_t* bgl = Blo + (size_t)(nBase + r_) * K + sg * 8;
  for (int k0 = 0; k0 < K; k0 += 32) {
#pragma unroll
    for (int it = 0; it < 2; ++it) {
      gl_lds16(agh + (size_t)(it * 64) * K + k0, Ah + it * 2048 + t * 8);
      gl_lds16(agl + (size_t)(it * 64) * K + k0, Al + it * 2048 + t * 8);
      gl_lds16(bgh + (size_t)(it * 64) * K + k0, Bh + it * 2048 + t * 8);
      gl_lds16(bgl + (size_t)(it * 64) * K + k0, Bl + it * 2048 + t * 8);
    }
    __syncthreads();
    bf16x8 ah[4], al[4], bh4[4], bl4[4];
#pragma unroll
    for (int i = 0; i < 4; ++i) {
      const int rA = wm + i * 16 + m16;
      const int offA = rA * 32 + ((quad ^ (rA & 3)) * 8);
      ah[i] = *(const bf16x8*)(Ah + offA);
      al[i] = *(const bf16x8*)(Al + offA);
      const int rB = wn + i * 16 + m16;
      const int offB = rB * 32 + ((quad ^ (rB & 3)) * 8);
      bh4[i] = *(const bf16x8*)(Bh + offB);
      bl4[i] = *(const bf16x8*)(Bl + offB);
    }
#pragma unroll
    for (int i = 0; i < 4; ++i)
#pragma unroll
      for (int j = 0; j < 4; ++j) {
        acc[i][j] = __builtin_amdgcn_mfma_f32_16x16x32_bf16(ah[i], bh4[j], acc[i][j], 0, 0, 0);
        acc[i][j] = __builtin_amdgcn_mfma_f32_16x16x32_bf16(ah[i], bl4[j], acc[i][j], 0, 0, 0);
        acc[i][j] = __builtin_amdgcn_mfma_f32_16x16x32_bf16(al[i], bh4[j], acc[i][j], 0, 0, 0);
      }
    __syncthreads();
  }
#pragma unroll
  for (int i = 0; i < 4; ++i) {
    const int row0 = mBase + wm + i * 16 + quad * 4;
#pragma unroll
    for (int j = 0; j < 4; ++j) {
      const int col = nBase + wn + j * 16 + m16;
#pragma unroll
      for (int r = 0; r < 4; ++r) {
        const size_t idx = (size_t)(row0 + r) * N + col;
        const float v = acc[i][j][r];
        const uint16_t hh = f2bf(v);
        Chi[idx] = hh;
        Clo[idx] = f2bf(v - bf2f(hh));
      }
    }
  }
}

// ---------------------------------- RoPE -----------------------------------
// In-place on split QK buffer [8192][2048] (cols 0..1023 Q, 1024..2047 K).

__global__ __launch_bounds__(256) void rope_k(uint16_t* __restrict__ qkh,
                                              uint16_t* __restrict__ qkl,
                                              const int* __restrict__ pos) {
  const int t = blockIdx.x * 256 + threadIdx.x;   // 8192*1024 pairs
  const int row = t >> 10, p = t & 1023;
  const int which = p >> 9, hp = p & 511, h = hp >> 5, d2 = hp & 31;
  const size_t idx = (size_t)row * 2048 + which * 1024 + h * 64 + d2 * 2;
  const uint32_t ph = *(const uint32_t*)(qkh + idx);
  const uint32_t pl = *(const uint32_t*)(qkl + idx);
  const float xe = bf2f(ph & 0xffffu) + bf2f(pl & 0xffffu);
  const float xo = bf2f(ph >> 16) + bf2f(pl >> 16);
  // inv_freq = 10000^(-d2/32) = exp2(-d2 * log2(10000)/32)
  const float inv_freq = exp2f((float)d2 * -0.41524101186092029f);
  const float fr = (float)pos[row & 2047] * inv_freq;
  float sn, cs; sincosf(fr, &sn, &cs);
  const float re = xe * cs - xo * sn;
  const float ro = xe * sn + xo * cs;
  const uint16_t reh = f2bf(re), roh = f2bf(ro);
  const uint16_t rel = f2bf(re - bf2f(reh)), rol = f2bf(ro - bf2f(roh));
  *(uint32_t*)(qkh + idx) = (uint32_t)reh | ((uint32_t)roh << 16);
  *(uint32_t*)(qkl + idx) = (uint32_t)rel | ((uint32_t)rol << 16);
}

// ----------------------- causal flash attention -----------------------------
// R7: double-buffered K/V LDS + counted vmcnt(6) prefetch; 2 raw s_barriers
// per KV-iter; wave-private P (no mid barrier); diag-only masking; exp2 fold.
// Grid (8,64); each block processes the q-tile PAIR (qt, 15-qt) = 34 KV-iters.
// R8: Vt layout is now [1024 d-rows][8192 tokens] (stride 8192, col b*2048+s).

__global__ __launch_bounds__(256) void flash_k(const uint16_t* __restrict__ Qh,
                                               const uint16_t* __restrict__ Ql,
                                               const uint16_t* __restrict__ Vt,
                                               uint16_t* __restrict__ Hout) {
  __shared__ __align__(16) uint16_t Kh[2][64 * 64];
  __shared__ __align__(16) uint16_t Kl[2][64 * 64];
  __shared__ __align__(16) uint16_t Vs[2][64 * 64];
  __shared__ __align__(16) uint16_t P[4][32 * 72];

  const int bh = blockIdx.y, b = bh >> 4, h = bh & 15;
  const int t = threadIdx.x, w = t >> 6, lane = t & 63, m16 = lane & 15, quad = lane >> 4;

  const int r_ = t >> 3, g_ = t & 7, sgx = g_ ^ (r_ & 7);
  const uint16_t* khg = Qh + (size_t)(b * 2048 + r_) * 2048 + 1024 + h * 64 + sgx * 8;
  const uint16_t* klg = Ql + (size_t)(b * 2048 + r_) * 2048 + 1024 + h * 64 + sgx * 8;
  const uint16_t* vtg = Vt + (size_t)(h * 64 + r_) * 8192 + (size_t)b * 2048 + sgx * 8;

  const float nscl = 0.18033688011112042f;   // log2(e)/8: fold 1/sqrt(64) + ln->log2

  for (int half = 0; half < 2; ++half) {
    const int qt = half ? (15 - (int)blockIdx.x) : (int)blockIdx.x;

    bf16x8 qh[2][2], ql[2][2];
#pragma unroll
    for (int i = 0; i < 2; ++i) {
      const int row = b * 2048 + qt * 128 + w * 32 + i * 16 + m16;
#pragma unroll
      for (int ks = 0; ks < 2; ++ks) {
        const size_t offq = (size_t)row * 2048 + h * 64 + ks * 32 + quad * 8;
        qh[i][ks] = *(const bf16x8*)(Qh + offq);
        ql[i][ks] = *(const bf16x8*)(Ql + offq);
      }
    }
    // Pin Q fragments: forces the compiler's vmcnt drain HERE, so inside the
    // loop the outstanding-VMEM count is exactly our 6 DMA loads per tile.
#pragma unroll
    for (int i = 0; i < 2; ++i)
#pragma unroll
      for (int ks = 0; ks < 2; ++ks)
        asm volatile("" : "+v"(qh[i][ks]), "+v"(ql[i][ks]));

    const int ktEnd = 2 * qt + 2;

    // prologue: stage tile 0 into buffer 0 (6 DMA loads in flight)
#pragma unroll
    for (int it = 0; it < 2; ++it) {
      gl_lds16(khg + (size_t)(it * 32) * 2048, &Kh[0][it * 2048 + t * 8]);
      gl_lds16(klg + (size_t)(it * 32) * 2048, &Kl[0][it * 2048 + t * 8]);
      gl_lds16(vtg + (size_t)(it * 32) * 8192, &Vs[0][it * 2048 + t * 8]);
    }

    float mr[2][4], lr[2][4];
    f32x4 o[2][4];
    const f32x4 vz = {0.f, 0.f, 0.f, 0.f};
#pragma unroll
    for (int i = 0; i < 2; ++i)
#pragma unroll
      for (int r = 0; r < 4; ++r) { mr[i][r] = -1e30f; lr[i][r] = 0.f; }
#pragma unroll
    for (int i = 0; i < 2; ++i)
#pragma unroll
      for (int n = 0; n < 4; ++n) o[i][n] = vz;

    for (int kt = 0; kt < ktEnd; ++kt) {
      const int cur = kt & 1, nxt = cur ^ 1;
      // guard: all waves finished READING buf[nxt] (its reads ended 2 iters
      // ago; every ds_read completes before its consuming MFMA, which
      // precedes this barrier in program order).
      __builtin_amdgcn_s_barrier();
      __builtin_amdgcn_sched_barrier(0);
      if (kt + 1 < ktEnd) {
        const int kn = kt + 1;
#pragma unroll
        for (int it = 0; it < 2; ++it) {
          gl_lds16(khg + (size_t)(kn * 64 + it * 32) * 2048, &Kh[nxt][it * 2048 + t * 8]);
          gl_lds16(klg + (size_t)(kn * 64 + it * 32) * 2048, &Kl[nxt][it * 2048 + t * 8]);
          gl_lds16(vtg + (size_t)(it * 32) * 8192 + kn * 64, &Vs[nxt][it * 2048 + t * 8]);
        }
        // drain tile kt's 6 loads; keep tile kt+1's 6 in flight (T4)
        asm volatile("s_waitcnt vmcnt(6)" ::: "memory");
      } else {
        asm volatile("s_waitcnt vmcnt(0)" ::: "memory");
      }
      __builtin_amdgcn_s_barrier();
      __builtin_amdgcn_sched_barrier(0);

      // ---- QK^T (3-pass hi/lo) on buf[cur] ----
      f32x4 sc[2][4];
#pragma unroll
      for (int i = 0; i < 2; ++i)
#pragma unroll
        for (int j = 0; j < 4; ++j) sc[i][j] = vz;
#pragma unroll
      for (int ks = 0; ks < 2; ++ks) {
        bf16x8 kfh[4], kfl[4];
        const int cg = ks * 4 + quad;
#pragma unroll
        for (int j = 0; j < 4; ++j) {
          const int rK = j * 16 + m16;
          const int offk = rK * 64 + ((cg ^ (rK & 7)) * 8);
          kfh[j] = *(const bf16x8*)(&Kh[cur][offk]);
          kfl[j] = *(const bf16x8*)(&Kl[cur][offk]);
        }
        __builtin_amdgcn_s_setprio(1);
#pragma unroll
        for (int i = 0; i < 2; ++i)
#pragma unroll
          for (int j = 0; j < 4; ++j) {
            sc[i][j] = __builtin_amdgcn_mfma_f32_16x16x32_bf16(qh[i][ks], kfh[j], sc[i][j], 0, 0, 0);
            sc[i][j] = __builtin_amdgcn_mfma_f32_16x16x32_bf16(qh[i][ks], kfl[j], sc[i][j], 0, 0, 0);
            sc[i][j] = __builtin_amdgcn_mfma_f32_16x16x32_bf16(ql[i][ks], kfh[j], sc[i][j], 0, 0, 0);
          }
        __builtin_amdgcn_s_setprio(0);
      }

      // ---- online softmax, raw-score domain (softmax is scale-invariant;
      //      P = exp2((s - m) * log2e/8), mask only on diagonal tiles) ----
#pragma unroll
      for (int i = 0; i < 2; ++i) {
        const bool needMask = (kt * 64 + 63) > (qt * 128 + w * 32 + i * 16);
#pragma unroll
        for (int r = 0; r < 4; ++r) {
          float mx = -1e30f;
          if (needMask) {
            const int qg = qt * 128 + w * 32 + i * 16 + quad * 4 + r;
#pragma unroll
            for (int j = 0; j < 4; ++j) {
              float v = sc[i][j][r];
              const int kg = kt * 64 + j * 16 + m16;
              if (kg > qg) v = -1e30f;
              sc[i][j][r] = v;
              mx = fmaxf(mx, v);
            }
          } else {
#pragma unroll
            for (int j = 0; j < 4; ++j) mx = fmaxf(mx, sc[i][j][r]);
          }
#pragma unroll
          for (int m = 1; m < 16; m <<= 1) mx = fmaxf(mx, __shfl_xor(mx, m));
          const float mnew = fmaxf(mr[i][r], mx);
          const float alpha = __builtin_amdgcn_exp2f((mr[i][r] - mnew) * nscl);
          mr[i][r] = mnew;
          const float nm = mnew * nscl;
          float ls = 0.f;
#pragma unroll
          for (int j = 0; j < 4; ++j) {
            const float pv = __builtin_amdgcn_exp2f(__builtin_fmaf(sc[i][j][r], nscl, -nm));
            sc[i][j][r] = pv;
            ls += pv;
          }
#pragma unroll
          for (int m = 1; m < 16; m <<= 1) ls += __shfl_xor(ls, m);
          lr[i][r] = lr[i][r] * alpha + ls;
#pragma unroll
          for (int n = 0; n < 4; ++n) o[i][n][r] *= alpha;
        }
#pragma unroll
        for (int j = 0; j < 4; ++j)
#pragma unroll
          for (int r = 0; r < 4; ++r)
            P[w][(i * 16 + quad * 4 + r) * 72 + j * 16 + m16] = f2bf(sc[i][j][r]);
      }
      // P[w] is wave-private: intra-wave ds_write->ds_read needs only the
      // compiler-inserted lgkmcnt, no cross-wave barrier.

#pragma unroll
      for (int ks2 = 0; ks2 < 2; ++ks2) {
        bf16x8 pf[2], vf[4];
#pragma unroll
        for (int i = 0; i < 2; ++i)
          pf[i] = *(const bf16x8*)(&P[w][(i * 16 + m16) * 72 + ks2 * 32 + quad * 8]);
        const int cg = ks2 * 4 + quad;
#pragma unroll
        for (int n = 0; n < 4; ++n) {
          const int rV = n * 16 + m16;
          vf[n] = *(const bf16x8*)(&Vs[cur][rV * 64 + ((cg ^ (rV & 7)) * 8)]);
        }
        __builtin_amdgcn_s_setprio(1);
#pragma unroll
        for (int i = 0; i < 2; ++i)
#pragma unroll
          for (int n = 0; n < 4; ++n)
            o[i][n] = __builtin_amdgcn_mfma_f32_16x16x32_bf16(pf[i], vf[n], o[i][n], 0, 0, 0);
        __builtin_amdgcn_s_setprio(0);
      }
    }

#pragma unroll
    for (int i = 0; i < 2; ++i)
#pragma unroll
      for (int r = 0; r < 4; ++r) {
        const float inv = 1.f / lr[i][r];
        const size_t row = (size_t)(b * 2048 + qt * 128 + w * 32 + i * 16 + quad * 4 + r);
#pragma unroll
        for (int n = 0; n < 4; ++n)
          Hout[row * 1024 + h * 64 + n * 16 + m16] = f2bf(o[i][n][r] * inv);
      }
    // full drain (vmcnt(0) incl. Hout stores) + barrier before the next half
    // re-stages buffer 0.
    __syncthreads();
  }
}

// ------------------------------ orchestration -------------------------------

extern "C" void kernel_launch(void* const* d_in, const int* in_sizes, int n_in,
                              void* d_out, int out_size, void* d_ws, size_t ws_size,
                              hipStream_t stream) {
  (void)in_sizes; (void)n_in; (void)out_size; (void)ws_size;
  const float* x   = (const float*)d_in[0];
  const int*   pos = (const int*)  d_in[1];
  const float* q_w = (const float*)d_in[2];
  const float* k_w = (const float*)d_in[3];
  const float* v_w = (const float*)d_in[4];
  const float* o_w = (const float*)d_in[5];
  const float* g1  = (const float*)d_in[6];
  const float* g2  = (const float*)d_in[7];
  const float* w1  = (const float*)d_in[8];
  const float* w2  = (const float*)d_in[9];
  const float* w3  = (const float*)d_in[10];

  char* ws = (char*)d_ws;
  uint16_t* wqk_hi = (uint16_t*)(ws + 0);
  uint16_t* wqk_lo = (uint16_t*)(ws + 4194304);
  uint16_t* wv     = (uint16_t*)(ws + 8388608);
  uint16_t* wo     = (uint16_t*)(ws + 10485760);
  uint16_t* w1b    = (uint16_t*)(ws + 12582912);
  uint16_t* w3b    = (uint16_t*)(ws + 20971520);
  uint16_t* w2b    = (uint16_t*)(ws + 29360128);
  uint16_t* xn_hi  = (uint16_t*)(ws + 37748736);
  uint16_t* xn_lo  = (uint16_t*)(ws + 54525952);
  uint16_t* vt     = (uint16_t*)(ws + 88080384);   // [1024][8192] bf16 = 16.7 MB
  uint16_t* qk_hi  = (uint16_t*)(ws + 104857600);
  uint16_t* qk_lo  = (uint16_t*)(ws + 138412032);
  uint16_t* hbuf   = (uint16_t*)(ws + 171966464);
  float*    ores   = (float*)   (ws + 188743680);
  uint16_t* on2    = (uint16_t*)(ws + 222298112);
  // overlays (regions dead by the time these are written):
  uint16_t* abuf   = (uint16_t*)(ws + 104857600);  // over qk_hi+qk_lo (67.1 MB)
  uint16_t* gbuf   = (uint16_t*)(ws + 37748736);   // over xn_hi..vt   (67.1 MB)
  // total ws required: 239,075,328 bytes

  cvt_split_qk_k<<<2048, 256, 0, stream>>>(q_w, k_w, wqk_hi, wqk_lo);
  cvt_bf16_k<<<1024, 256, 0, stream>>>(v_w, wv, 262144);
  cvt_bf16_k<<<1024, 256, 0, stream>>>(o_w, wo, 262144);
  cvt_bf16_k<<<4096, 256, 0, stream>>>(w1, w1b, 1048576);
  cvt_bf16_k<<<4096, 256, 0, stream>>>(w3, w3b, 1048576);
  cvt_bf16_k<<<4096, 256, 0, stream>>>(w2, w2b, 1048576);

  rmsnorm_k<true><<<8192, 256, 0, stream>>>(x, g1, xn_hi, xn_lo);

  gemm_bt_split_k<<<dim3(16, 64), 256, 0, stream>>>(xn_hi, xn_lo, wqk_hi, wqk_lo,
                                                    qk_hi, qk_lo, 2048, 1024);
  // V^T directly: Vt[1024][8192] = Wv @ Xn^T (operand swap = free transpose)
  gemm_bt_k<0><<<dim3(64, 8), 256, 0, stream>>>(wv, xn_hi, (void*)vt, nullptr, 8192, 1024);

  rope_k<<<32768, 256, 0, stream>>>(qk_hi, qk_lo, pos);

  flash_k<<<dim3(8, 64), 256, 0, stream>>>(qk_hi, qk_lo, vt, hbuf);

  gemm_bt_k<1><<<dim3(8, 64), 256, 0, stream>>>(hbuf, wo, (void*)ores, x, 1024, 1024);

  rmsnorm_k<false><<<8192, 256, 0, stream>>>(ores, g2, on2, nullptr);

  gemm256_k<0><<<dim3(16, 32), 512, 0, stream>>>(on2, w1b, abuf, nullptr, 4096, 1024);
  gemm256_k<2><<<dim3(16, 32), 512, 0, stream>>>(on2, w3b, gbuf, abuf, 4096, 1024);

  gemm_bt_k<1><<<dim3(8, 64), 256, 0, stream>>>(gbuf, w2b, d_out, ores, 1024, 4096);
}